// Round 1
// baseline (917.848 us; speedup 1.0000x reference)
//
#include <hip/hip_runtime.h>

#define NN 100000
#define NE 1600000
#define NG 1024
#define NODE_IN 163
#define SLOPE 0.01f

__global__ void k_count(const int* __restrict__ dst, int* __restrict__ cnt, int E) {
  int i = blockIdx.x * 256 + threadIdx.x;
  if (i < E) atomicAdd(&cnt[dst[i]], 1);
}

__global__ void k_partial(const int* __restrict__ cnt, int* __restrict__ bsums, int N) {
  __shared__ int s[256];
  int tid = threadIdx.x;
  int i = blockIdx.x * 256 + tid;
  s[tid] = (i < N) ? cnt[i] : 0;
  __syncthreads();
  for (int st = 128; st > 0; st >>= 1) {
    if (tid < st) s[tid] += s[tid + st];
    __syncthreads();
  }
  if (tid == 0) bsums[blockIdx.x] = s[0];
}

__global__ void k_scan_bsums(int* __restrict__ bs, int nb) {
  __shared__ int s[512];
  int tid = threadIdx.x;
  int v = (tid < nb) ? bs[tid] : 0;
  s[tid] = v;
  __syncthreads();
  for (int off = 1; off < 512; off <<= 1) {
    int t = (tid >= off) ? s[tid - off] : 0;
    __syncthreads();
    s[tid] += t;
    __syncthreads();
  }
  if (tid < nb) bs[tid] = s[tid] - v;   // exclusive block offsets
}

__global__ void k_scan_final(const int* __restrict__ cnt, const int* __restrict__ bs,
                             int* __restrict__ offs, int* __restrict__ cursor, int N, int E) {
  __shared__ int s[256];
  int tid = threadIdx.x;
  int i = blockIdx.x * 256 + tid;
  int v = (i < N) ? cnt[i] : 0;
  s[tid] = v;
  __syncthreads();
  for (int off = 1; off < 256; off <<= 1) {
    int t = (tid >= off) ? s[tid - off] : 0;
    __syncthreads();
    s[tid] += t;
    __syncthreads();
  }
  int o = bs[blockIdx.x] + s[tid] - v;
  if (i < N) { offs[i] = o; cursor[i] = o; }
  if (blockIdx.x == 0 && tid == 0) offs[N] = E;
}

__global__ void k_dis(const int* __restrict__ cnt, float* __restrict__ dis, int N) {
  int i = blockIdx.x * 256 + threadIdx.x;
  if (i < N) dis[i] = rsqrtf((float)(cnt[i] + 1));
}

__global__ void k_fill(const int* __restrict__ src, const int* __restrict__ dst,
                       int* __restrict__ cursor, int* __restrict__ csr, int E) {
  int i = blockIdx.x * 256 + threadIdx.x;
  if (i < E) {
    int d = dst[i];
    int pos = atomicAdd(&cursor[d], 1);
    csr[pos] = src[i];
  }
}

// Y[N,64] = X[N,K] @ W[K,64].  Block = 4 waves; wave handles 4 rows, lane = column.
template<int K, int KP>
__launch_bounds__(256)
__global__ void k_gemm(const float* __restrict__ X, const float* __restrict__ W,
                       float* __restrict__ Y, int N) {
  __shared__ float sW[K * 64];
  __shared__ float sX[16][KP];
  const int tid = threadIdx.x;
  for (int i = tid; i < K * 64; i += 256) sW[i] = W[i];
  const int lane = tid & 63;
  const int r0 = (tid >> 6) * 4;
  for (int tile = blockIdx.x * 16; tile < N; tile += gridDim.x * 16) {
    __syncthreads();
    for (int i = tid; i < 16 * K; i += 256) {
      int r = i / K, k = i - r * K;
      int gr = tile + r;
      sX[r][k] = (gr < N) ? X[(size_t)gr * K + k] : 0.f;
    }
    __syncthreads();
    float a0 = 0.f, a1 = 0.f, a2 = 0.f, a3 = 0.f;
    #pragma unroll 4
    for (int k = 0; k < K; ++k) {
      float wv = sW[k * 64 + lane];
      a0 += sX[r0 + 0][k] * wv;
      a1 += sX[r0 + 1][k] * wv;
      a2 += sX[r0 + 2][k] * wv;
      a3 += sX[r0 + 3][k] * wv;
    }
    int gr = tile + r0;
    if (gr + 0 < N) Y[(size_t)(gr + 0) * 64 + lane] = a0;
    if (gr + 1 < N) Y[(size_t)(gr + 1) * 64 + lane] = a1;
    if (gr + 2 < N) Y[(size_t)(gr + 2) * 64 + lane] = a2;
    if (gr + 3 < N) Y[(size_t)(gr + 3) * 64 + lane] = a3;
  }
}

// One wave per node: out[i] = lrelu( sum_{e->i} Hp[src]*dis[src]*dis[i] + Hp[i]/deg[i] + b )
__launch_bounds__(256)
__global__ void k_agg(const float* __restrict__ Hp, const int* __restrict__ offs,
                      const int* __restrict__ csr, const float* __restrict__ dis,
                      const float* __restrict__ bias, float* __restrict__ Hout, int N) {
  int node = blockIdx.x * 4 + (threadIdx.x >> 6);
  if (node >= N) return;
  int lane = threadIdx.x & 63;
  float di = dis[node];
  int beg = offs[node], end = offs[node + 1];
  float acc = Hp[(size_t)node * 64 + lane] * (di * di);
  for (int e = beg; e < end; ++e) {
    int s = csr[e];
    acc += Hp[(size_t)s * 64 + lane] * (di * dis[s]);
  }
  acc += bias[lane];
  Hout[(size_t)node * 64 + lane] = (acc > 0.f) ? acc : SLOPE * acc;
}

// One wave per graph: mean-pool (batch sorted -> binary-search bounds) + fc1 + lrelu + fc2.
__launch_bounds__(64)
__global__ void k_pool(const float* __restrict__ H, const int* __restrict__ batch,
                       const float* __restrict__ f1W, const float* __restrict__ f1b,
                       const float* __restrict__ f2W, const float* __restrict__ f2b,
                       float* __restrict__ out, int N) {
  int g = blockIdx.x;
  int lane = threadIdx.x;
  int lo = 0, hi = N;
  while (lo < hi) { int m = (lo + hi) >> 1; if (batch[m] < g) lo = m + 1; else hi = m; }
  int beg = lo;
  hi = N;
  while (lo < hi) { int m = (lo + hi) >> 1; if (batch[m] < g + 1) lo = m + 1; else hi = m; }
  int end = lo;
  float acc = 0.f;
  for (int r = beg; r < end; ++r) acc += H[(size_t)r * 64 + lane];
  float c = (float)(end - beg);
  acc /= (c < 1.f ? 1.f : c);
  __shared__ float p[64];
  p[lane] = acc;
  __syncthreads();
  float q = f1b[lane];
  #pragma unroll
  for (int k = 0; k < 64; ++k) q += p[k] * f1W[k * 64 + lane];
  q = (q > 0.f) ? q : SLOPE * q;
  float v = q * f2W[lane];
  #pragma unroll
  for (int off = 32; off > 0; off >>= 1) v += __shfl_down(v, off, 64);
  if (lane == 0) out[g] = v + f2b[0];
}

extern "C" void kernel_launch(void* const* d_in, const int* in_sizes, int n_in,
                              void* d_out, int out_size, void* d_ws, size_t ws_size,
                              hipStream_t stream) {
  const float* x   = (const float*)d_in[0];
  const int*  eidx = (const int*)d_in[1];
  const int*  batch= (const int*)d_in[2];
  const float* W0 = (const float*)d_in[3];
  const float* b0 = (const float*)d_in[4];
  const float* W1 = (const float*)d_in[5];
  const float* b1 = (const float*)d_in[6];
  const float* W2 = (const float*)d_in[7];
  const float* b2 = (const float*)d_in[8];
  const float* f1W = (const float*)d_in[9];
  const float* f1b = (const float*)d_in[10];
  const float* f2W = (const float*)d_in[11];
  const float* f2b = (const float*)d_in[12];
  float* out = (float*)d_out;

  const int N = NN, E = NE;
  const int* src  = eidx;
  const int* dstp = eidx + E;

  char* w = (char*)d_ws;
  float* bufA  = (float*)w; w += (size_t)N * 64 * 4;
  float* bufB  = (float*)w; w += (size_t)N * 64 * 4;
  int*   cnt   = (int*)w;   w += (size_t)N * 4;
  int*   offs  = (int*)w;   w += (size_t)(N + 4) * 4;
  int*   cursor= (int*)w;   w += (size_t)N * 4;
  int*   csr   = (int*)w;   w += (size_t)E * 4;
  float* dis   = (float*)w; w += (size_t)N * 4;
  int*   bsums = (int*)w;   w += 512 * 4;

  hipMemsetAsync(cnt, 0, (size_t)N * 4, stream);
  const int NB = (N + 255) / 256;           // 391 <= 512
  k_count<<<(E + 255) / 256, 256, 0, stream>>>(dstp, cnt, E);
  k_partial<<<NB, 256, 0, stream>>>(cnt, bsums, N);
  k_scan_bsums<<<1, 512, 0, stream>>>(bsums, NB);
  k_scan_final<<<NB, 256, 0, stream>>>(cnt, bsums, offs, cursor, N, E);
  k_dis<<<NB, 256, 0, stream>>>(cnt, dis, N);
  k_fill<<<(E + 255) / 256, 256, 0, stream>>>(src, dstp, cursor, csr, E);

  k_gemm<NODE_IN, 164><<<1024, 256, 0, stream>>>(x, W0, bufA, N);
  k_agg<<<(N + 3) / 4, 256, 0, stream>>>(bufA, offs, csr, dis, b0, bufB, N);
  k_gemm<64, 64><<<1024, 256, 0, stream>>>(bufB, W1, bufA, N);
  k_agg<<<(N + 3) / 4, 256, 0, stream>>>(bufA, offs, csr, dis, b1, bufB, N);
  k_gemm<64, 64><<<1024, 256, 0, stream>>>(bufB, W2, bufA, N);
  k_agg<<<(N + 3) / 4, 256, 0, stream>>>(bufA, offs, csr, dis, b2, bufB, N);
  k_pool<<<NG, 64, 0, stream>>>(bufB, batch, f1W, f1b, f2W, f2b, out, N);
}

// Round 2
// 676.103 us; speedup vs baseline: 1.3576x; 1.3576x over previous
//
#include <hip/hip_runtime.h>

#define NN 100000
#define NE 1600000
#define NG 1024
#define NODE_IN 163
#define SLOPE 0.01f

__global__ void k_count(const int* __restrict__ dst, int* __restrict__ cnt, int E) {
  int i = blockIdx.x * 256 + threadIdx.x;
  if (i < E) atomicAdd(&cnt[dst[i]], 1);
}

__global__ void k_partial(const int* __restrict__ cnt, int* __restrict__ bsums, int N) {
  __shared__ int s[256];
  int tid = threadIdx.x;
  int i = blockIdx.x * 256 + tid;
  s[tid] = (i < N) ? cnt[i] : 0;
  __syncthreads();
  for (int st = 128; st > 0; st >>= 1) {
    if (tid < st) s[tid] += s[tid + st];
    __syncthreads();
  }
  if (tid == 0) bsums[blockIdx.x] = s[0];
}

__global__ void k_scan_bsums(int* __restrict__ bs, int nb) {
  __shared__ int s[512];
  int tid = threadIdx.x;
  int v = (tid < nb) ? bs[tid] : 0;
  s[tid] = v;
  __syncthreads();
  for (int off = 1; off < 512; off <<= 1) {
    int t = (tid >= off) ? s[tid - off] : 0;
    __syncthreads();
    s[tid] += t;
    __syncthreads();
  }
  if (tid < nb) bs[tid] = s[tid] - v;   // exclusive block offsets
}

__global__ void k_scan_final(const int* __restrict__ cnt, const int* __restrict__ bs,
                             int* __restrict__ offs, int* __restrict__ cursor, int N, int E) {
  __shared__ int s[256];
  int tid = threadIdx.x;
  int i = blockIdx.x * 256 + tid;
  int v = (i < N) ? cnt[i] : 0;
  s[tid] = v;
  __syncthreads();
  for (int off = 1; off < 256; off <<= 1) {
    int t = (tid >= off) ? s[tid - off] : 0;
    __syncthreads();
    s[tid] += t;
    __syncthreads();
  }
  int o = bs[blockIdx.x] + s[tid] - v;
  if (i < N) { offs[i] = o; cursor[i] = o; }
  if (blockIdx.x == 0 && tid == 0) offs[N] = E;
}

__global__ void k_dis(const int* __restrict__ cnt, float* __restrict__ dis, int N) {
  int i = blockIdx.x * 256 + threadIdx.x;
  if (i < N) dis[i] = rsqrtf((float)(cnt[i] + 1));
}

__global__ void k_fill(const int* __restrict__ src, const int* __restrict__ dst,
                       int* __restrict__ cursor, int* __restrict__ csr, int E) {
  int i = blockIdx.x * 256 + threadIdx.x;
  if (i < E) {
    int d = dst[i];
    int pos = atomicAdd(&cursor[d], 1);
    csr[pos] = src[i];
  }
}

// Y[N,64] = (X[N,K] @ W[K,64]) * dis[row].  64-row tile/block, 4x4 microtile/thread.
template<int K>
__launch_bounds__(256)
__global__ void k_gemm(const float* __restrict__ X, const float* __restrict__ W,
                       const float* __restrict__ disv, float* __restrict__ Y, int N) {
  constexpr int BK = 32;
  constexpr int KS = (K + BK - 1) / BK;
  __shared__ float sW[BK][64];
  __shared__ float sX[64][BK + 4];
  const int tid = threadIdx.x;
  const int wave = tid >> 6, lane = tid & 63;
  const int lr = lane >> 4, lc = lane & 15;
  const int r0 = wave * 16 + lr * 4;
  const int c0 = lc * 4;
  const int tile = blockIdx.x * 64;
  float acc[4][4] = {};

  for (int ks = 0; ks < KS; ++ks) {
    const int k0 = ks * BK;
    __syncthreads();
    #pragma unroll
    for (int i = tid; i < BK * 64; i += 256) {        // stage W (k-major)
      int kk = i >> 6, cc = i & 63;
      sW[kk][cc] = (k0 + kk < K) ? W[(size_t)(k0 + kk) * 64 + cc] : 0.f;
    }
    #pragma unroll
    for (int i = tid; i < 64 * BK; i += 256) {        // stage X (row-major, padded)
      int rr = i >> 5, kk = i & 31;
      int gr = tile + rr, k = k0 + kk;
      sX[rr][kk] = (gr < N && k < K) ? X[(size_t)gr * K + k] : 0.f;
    }
    __syncthreads();
    #pragma unroll
    for (int k = 0; k < BK; k += 4) {
      float4 xv[4], wv[4];
      #pragma unroll
      for (int i = 0; i < 4; ++i) xv[i] = *(const float4*)&sX[r0 + i][k];
      #pragma unroll
      for (int j = 0; j < 4; ++j) wv[j] = *(const float4*)&sW[k + j][c0];
      #pragma unroll
      for (int i = 0; i < 4; ++i) {
        acc[i][0] += xv[i].x * wv[0].x; acc[i][1] += xv[i].x * wv[0].y;
        acc[i][2] += xv[i].x * wv[0].z; acc[i][3] += xv[i].x * wv[0].w;
        acc[i][0] += xv[i].y * wv[1].x; acc[i][1] += xv[i].y * wv[1].y;
        acc[i][2] += xv[i].y * wv[1].z; acc[i][3] += xv[i].y * wv[1].w;
        acc[i][0] += xv[i].z * wv[2].x; acc[i][1] += xv[i].z * wv[2].y;
        acc[i][2] += xv[i].z * wv[2].z; acc[i][3] += xv[i].z * wv[2].w;
        acc[i][0] += xv[i].w * wv[3].x; acc[i][1] += xv[i].w * wv[3].y;
        acc[i][2] += xv[i].w * wv[3].z; acc[i][3] += xv[i].w * wv[3].w;
      }
    }
  }
  #pragma unroll
  for (int i = 0; i < 4; ++i) {
    int gr = tile + r0 + i;
    if (gr < N) {
      float d = disv[gr];
      float4 o = make_float4(acc[i][0] * d, acc[i][1] * d, acc[i][2] * d, acc[i][3] * d);
      *(float4*)&Y[(size_t)gr * 64 + c0] = o;
    }
  }
}

// One wave per node: Hout[i] = lrelu( (Hps[i] + sum_{e->i} Hps[src]) * dis[i] + b )
__launch_bounds__(256)
__global__ void k_agg(const float* __restrict__ Hps, const int* __restrict__ offs,
                      const int* __restrict__ csr, const float* __restrict__ dis,
                      const float* __restrict__ bias, float* __restrict__ Hout, int N) {
  int node = blockIdx.x * 4 + (threadIdx.x >> 6);
  if (node >= N) return;
  int lane = threadIdx.x & 63;
  int beg = offs[node], end = offs[node + 1];
  float acc = Hps[(size_t)node * 64 + lane];
  int e = beg;
  for (; e + 4 <= end; e += 4) {
    int s0 = csr[e], s1 = csr[e + 1], s2 = csr[e + 2], s3 = csr[e + 3];
    acc += Hps[(size_t)s0 * 64 + lane];
    acc += Hps[(size_t)s1 * 64 + lane];
    acc += Hps[(size_t)s2 * 64 + lane];
    acc += Hps[(size_t)s3 * 64 + lane];
  }
  for (; e < end; ++e) acc += Hps[(size_t)csr[e] * 64 + lane];
  acc = acc * dis[node] + bias[lane];
  Hout[(size_t)node * 64 + lane] = (acc > 0.f) ? acc : SLOPE * acc;
}

// One wave per graph: mean-pool (batch sorted -> binary-search bounds) + fc1 + lrelu + fc2.
__launch_bounds__(64)
__global__ void k_pool(const float* __restrict__ H, const int* __restrict__ batch,
                       const float* __restrict__ f1W, const float* __restrict__ f1b,
                       const float* __restrict__ f2W, const float* __restrict__ f2b,
                       float* __restrict__ out, int N) {
  int g = blockIdx.x;
  int lane = threadIdx.x;
  int lo = 0, hi = N;
  while (lo < hi) { int m = (lo + hi) >> 1; if (batch[m] < g) lo = m + 1; else hi = m; }
  int beg = lo;
  hi = N;
  while (lo < hi) { int m = (lo + hi) >> 1; if (batch[m] < g + 1) lo = m + 1; else hi = m; }
  int end = lo;
  float acc = 0.f;
  for (int r = beg; r < end; ++r) acc += H[(size_t)r * 64 + lane];
  float c = (float)(end - beg);
  acc /= (c < 1.f ? 1.f : c);
  __shared__ float p[64];
  p[lane] = acc;
  __syncthreads();
  float q = f1b[lane];
  #pragma unroll
  for (int k = 0; k < 64; ++k) q += p[k] * f1W[k * 64 + lane];
  q = (q > 0.f) ? q : SLOPE * q;
  float v = q * f2W[lane];
  #pragma unroll
  for (int off = 32; off > 0; off >>= 1) v += __shfl_down(v, off, 64);
  if (lane == 0) out[g] = v + f2b[0];
}

extern "C" void kernel_launch(void* const* d_in, const int* in_sizes, int n_in,
                              void* d_out, int out_size, void* d_ws, size_t ws_size,
                              hipStream_t stream) {
  const float* x   = (const float*)d_in[0];
  const int*  eidx = (const int*)d_in[1];
  const int*  batch= (const int*)d_in[2];
  const float* W0 = (const float*)d_in[3];
  const float* b0 = (const float*)d_in[4];
  const float* W1 = (const float*)d_in[5];
  const float* b1 = (const float*)d_in[6];
  const float* W2 = (const float*)d_in[7];
  const float* b2 = (const float*)d_in[8];
  const float* f1W = (const float*)d_in[9];
  const float* f1b = (const float*)d_in[10];
  const float* f2W = (const float*)d_in[11];
  const float* f2b = (const float*)d_in[12];
  float* out = (float*)d_out;

  const int N = NN, E = NE;
  const int* src  = eidx;
  const int* dstp = eidx + E;

  char* w = (char*)d_ws;
  float* bufA  = (float*)w; w += (size_t)N * 64 * 4;
  float* bufB  = (float*)w; w += (size_t)N * 64 * 4;
  int*   cnt   = (int*)w;   w += (size_t)N * 4;
  int*   offs  = (int*)w;   w += (size_t)(N + 4) * 4;
  int*   cursor= (int*)w;   w += (size_t)N * 4;
  int*   csr   = (int*)w;   w += (size_t)E * 4;
  float* dis   = (float*)w; w += (size_t)N * 4;
  int*   bsums = (int*)w;   w += 512 * 4;

  hipMemsetAsync(cnt, 0, (size_t)N * 4, stream);
  const int NB = (N + 255) / 256;           // 391 <= 512
  k_count<<<(E + 255) / 256, 256, 0, stream>>>(dstp, cnt, E);
  k_partial<<<NB, 256, 0, stream>>>(cnt, bsums, N);
  k_scan_bsums<<<1, 512, 0, stream>>>(bsums, NB);
  k_scan_final<<<NB, 256, 0, stream>>>(cnt, bsums, offs, cursor, N, E);
  k_dis<<<NB, 256, 0, stream>>>(cnt, dis, N);
  k_fill<<<(E + 255) / 256, 256, 0, stream>>>(src, dstp, cursor, csr, E);

  const int GB = (N + 63) / 64;
  k_gemm<NODE_IN><<<GB, 256, 0, stream>>>(x, W0, dis, bufA, N);
  k_agg<<<(N + 3) / 4, 256, 0, stream>>>(bufA, offs, csr, dis, b0, bufB, N);
  k_gemm<64><<<GB, 256, 0, stream>>>(bufB, W1, dis, bufA, N);
  k_agg<<<(N + 3) / 4, 256, 0, stream>>>(bufA, offs, csr, dis, b1, bufB, N);
  k_gemm<64><<<GB, 256, 0, stream>>>(bufB, W2, dis, bufA, N);
  k_agg<<<(N + 3) / 4, 256, 0, stream>>>(bufA, offs, csr, dis, b2, bufB, N);
  k_pool<<<NG, 64, 0, stream>>>(bufB, batch, f1W, f1b, f2W, f2b, out, N);
}